// Round 3
// baseline (171.620 us; speedup 1.0000x reference)
//
#include <hip/hip_runtime.h>

#define Bn   4
#define CIN  32
#define COUT 32
#define CG   8
#define Hh   128
#define Ww   128
#define KK   5
#define HW   (Hh * Ww)
#define TS   16     // 16x16 pixel tile per block
#define PR   20     // patch region (TS + 4)
#define PSTR 24     // LDS row stride: 2-way bank aliasing only (free per m136)
#define JG   8      // x channels staged per group

// block = 256 threads = 16x16 pixel tile; blockIdx.y = output quarter (8 ch).
// Tap-major inner loop: one LDS read + one mul per tap, then 8 FMAs against
// wave-uniform (scalar-loaded) weights. No xv[] array -> no spills.
__global__ __launch_bounds__(256, 4) void pac_lds2(
    const float* __restrict__ x, const float* __restrict__ guide,
    const float* __restrict__ weight, const float* __restrict__ bias,
    float* __restrict__ out)
{
    __shared__ float sx[JG][PR * PSTR];   // 8 * 20*24 * 4B = 15.36 KB

    const int tid = threadIdx.x;
    const int tx = tid & (TS - 1), ty = tid >> 4;
    const int tile = blockIdx.x;              // 0..63
    const int quarter = blockIdx.y;           // 0..3
    const int b = blockIdx.z;
    const int tm = (tile >> 3) * TS, tn = (tile & 7) * TS;
    const int m = tm + ty, n = tn + tx;

    // ---- adaptive kernel from guide (global loads, once per pixel) ----
    const float* gb = guide + ((size_t)b * CG) * HW + m * Ww + n;
    float center[CG];
#pragma unroll
    for (int c = 0; c < CG; ++c) center[c] = gb[c * HW];

    float kern[KK * KK];
#pragma unroll
    for (int k = 0; k < KK; ++k) {
        const int dm = k - 2;
        const bool rowok = ((unsigned)(m + dm) < (unsigned)Hh);
#pragma unroll
        for (int l = 0; l < KK; ++l) {
            const int dn = l - 2;
            const bool ok = rowok && ((unsigned)(n + dn) < (unsigned)Ww);
            float ss = 0.f;
#pragma unroll
            for (int c = 0; c < CG; ++c) {
                float gv = ok ? gb[c * HW + dm * Ww + dn] : 0.f;
                float d = gv - center[c];
                ss = fmaf(d, d, ss);
            }
            kern[k * KK + l] = __expf(-0.5f * ss);
        }
    }

    // ---- convolution: LDS-staged x, tap-major, scalar weights ----
    float acc[8];
#pragma unroll
    for (int o = 0; o < 8; ++o) acc[o] = 0.f;

    const int obase = quarter * 8;
    const float* wq = weight + (size_t)obase * (CIN * KK * KK);
    const float* xb = x + ((size_t)b * CIN) * HW;

    for (int g = 0; g < CIN / JG; ++g) {
        if (g) __syncthreads();
        // stage JG channels of the 20x20 halo tile, zero-padded
        for (int idx = tid; idx < JG * PR * PR; idx += 256) {
            const int ch = idx / (PR * PR);
            const int rem = idx - ch * (PR * PR);
            const int r = rem / PR, c = rem - r * PR;
            const int gm = tm - 2 + r, gn = tn - 2 + c;
            float v = 0.f;
            if ((unsigned)gm < (unsigned)Hh && (unsigned)gn < (unsigned)Ww)
                v = xb[(size_t)(g * JG + ch) * HW + gm * Ww + gn];
            sx[ch][r * PSTR + c] = v;
        }
        __syncthreads();

#pragma unroll
        for (int jj = 0; jj < JG; ++jj) {
            const float* srow = &sx[jj][ty * PSTR + tx];
            const int j = g * JG + jj;
            const float* wj = wq + j * (KK * KK);
#pragma unroll
            for (int k = 0; k < KK; ++k) {
#pragma unroll
                for (int l = 0; l < KK; ++l) {
                    const float v = srow[k * PSTR + l] * kern[k * KK + l];
#pragma unroll
                    for (int o = 0; o < 8; ++o)
                        acc[o] = fmaf(v, wj[(size_t)o * (CIN * KK * KK) + k * KK + l], acc[o]);
                }
            }
        }
    }

    float* op = out + ((size_t)b * COUT) * HW + m * Ww + n;
#pragma unroll
    for (int o = 0; o < 8; ++o)
        op[(size_t)(obase + o) * HW] = acc[o] + bias[obase + o];
}

extern "C" void kernel_launch(void* const* d_in, const int* in_sizes, int n_in,
                              void* d_out, int out_size, void* d_ws, size_t ws_size,
                              hipStream_t stream) {
    const float* x      = (const float*)d_in[0];
    const float* guide  = (const float*)d_in[1];
    const float* weight = (const float*)d_in[2];
    const float* bias   = (const float*)d_in[3];
    float* out = (float*)d_out;

    dim3 grid(64, 4, Bn);   // 64 tiles * 4 output-quarters * 4 batches = 1024 blocks
    pac_lds2<<<grid, dim3(256), 0, stream>>>(x, guide, weight, bias, out);
}

// Round 4
// 152.462 us; speedup vs baseline: 1.1257x; 1.1257x over previous
//
#include <hip/hip_runtime.h>

#define Bn   4
#define CIN  32
#define COUT 32
#define CG   8
#define Hh   128
#define Ww   128
#define KK   5
#define HW   (Hh * Ww)
#define TSW  64     // tile: 64 wide x 4 tall -> wave = one full output row
#define TSH  4
#define PRW  68     // halo region 68 x 8
#define PRH  8
#define PSTR 69     // LDS row stride (dwords); lane-consecutive reads stay conflict-free
#define JG   16     // channels staged per group (2 groups)

// block = 256 threads = 64x4 pixel tile; blockIdx.y = output half (16 ch).
// Wave = one output row -> 256B contiguous stores. x staged through LDS
// (zero-padded halo, static indexing). Weights via wave-uniform scalar loads.
__global__ __launch_bounds__(256, 2) void pac_v4(
    const float* __restrict__ x, const float* __restrict__ guide,
    const float* __restrict__ weight, const float* __restrict__ bias,
    float* __restrict__ out)
{
    __shared__ float sx[JG][PRH * PSTR];   // 16 * 8*69 * 4B = 35,328 B

    const int tid = threadIdx.x;
    const int tx = tid & 63;               // col within tile (= lane)
    const int ty = tid >> 6;               // row within tile 0..3 (= wave id)
    const int tile = blockIdx.x;           // 0..63
    const int half = blockIdx.y;           // 0..1
    const int b = blockIdx.z;
    const int tm = (tile >> 1) * TSH;      // 32 row-groups
    const int tn = (tile & 1) * TSW;       // 2 col-groups
    const int m = tm + ty, n = tn + tx;

    // ---- adaptive kernel from guide (global loads, once per pixel) ----
    const float* gb = guide + ((size_t)b * CG) * HW + m * Ww + n;
    float center[CG];
#pragma unroll
    for (int c = 0; c < CG; ++c) center[c] = gb[c * HW];

    float kern[KK * KK];
#pragma unroll
    for (int k = 0; k < KK; ++k) {
        const int dm = k - 2;
        const bool rowok = ((unsigned)(m + dm) < (unsigned)Hh);
#pragma unroll
        for (int l = 0; l < KK; ++l) {
            const int dn = l - 2;
            const bool ok = rowok && ((unsigned)(n + dn) < (unsigned)Ww);
            float ss = 0.f;
#pragma unroll
            for (int c = 0; c < CG; ++c) {
                float gv = ok ? gb[c * HW + dm * Ww + dn] : 0.f;
                float d = gv - center[c];
                ss = fmaf(d, d, ss);
            }
            kern[k * KK + l] = __expf(-0.5f * ss);
        }
    }

    // ---- convolution ----
    float acc[16];
#pragma unroll
    for (int o = 0; o < 16; ++o) acc[o] = 0.f;

    const int obase = half * 16;
    const float* wq = weight + (size_t)obase * (CIN * KK * KK);
    const float* xb = x + ((size_t)b * CIN) * HW;

    for (int g = 0; g < CIN / JG; ++g) {
        if (g) __syncthreads();
        // stage 16 channels of the 68x8 halo tile, zero-padded, static indexing
        for (int ch = 0; ch < JG; ++ch) {
            const float* xc = xb + (size_t)(g * JG + ch) * HW;
#pragma unroll
            for (int rr = 0; rr < 2; ++rr) {
                const int r = ty + 4 * rr;             // 0..7
                const int gm = tm - 2 + r;
                const bool rok = ((unsigned)gm < (unsigned)Hh);
                {
                    const int gn = tn - 2 + tx;
                    float v = (rok && (unsigned)gn < (unsigned)Ww) ? xc[gm * Ww + gn] : 0.f;
                    sx[ch][r * PSTR + tx] = v;
                }
                if (tx < PRW - 64) {                   // 4 tail columns
                    const int c = 64 + tx;
                    const int gn = tn - 2 + c;
                    float v = (rok && (unsigned)gn < (unsigned)Ww) ? xc[gm * Ww + gn] : 0.f;
                    sx[ch][r * PSTR + c] = v;
                }
            }
        }
        __syncthreads();

        for (int jj = 0; jj < JG; ++jj) {
            const float* srow = &sx[jj][ty * PSTR + tx];
            float xv[KK * KK];
#pragma unroll
            for (int k = 0; k < KK; ++k)
#pragma unroll
                for (int l = 0; l < KK; ++l)
                    xv[k * KK + l] = srow[k * PSTR + l] * kern[k * KK + l];

            const int j = g * JG + jj;
            const float* wj = wq + j * (KK * KK);
#pragma unroll
            for (int o = 0; o < 16; ++o) {
                const float* wo = wj + (size_t)o * (CIN * KK * KK);  // 25 contiguous, wave-uniform
                float a = acc[o];
#pragma unroll
                for (int t = 0; t < KK * KK; ++t)
                    a = fmaf(xv[t], wo[t], a);
                acc[o] = a;
            }
        }
    }

    float* op = out + ((size_t)b * COUT + obase) * HW + m * Ww + n;
#pragma unroll
    for (int o = 0; o < 16; ++o)
        op[(size_t)o * HW] = acc[o] + bias[obase + o];
}

extern "C" void kernel_launch(void* const* d_in, const int* in_sizes, int n_in,
                              void* d_out, int out_size, void* d_ws, size_t ws_size,
                              hipStream_t stream) {
    const float* x      = (const float*)d_in[0];
    const float* guide  = (const float*)d_in[1];
    const float* weight = (const float*)d_in[2];
    const float* bias   = (const float*)d_in[3];
    float* out = (float*)d_out;

    dim3 grid(64, 2, Bn);   // 64 tiles * 2 output-halves * 4 batches = 512 blocks
    pac_v4<<<grid, dim3(256), 0, stream>>>(x, guide, weight, bias, out);
}

// Round 5
// 106.448 us; speedup vs baseline: 1.6122x; 1.4323x over previous
//
#include <hip/hip_runtime.h>

#define Bn   4
#define CIN  32
#define COUT 32
#define CG   8
#define Hh   128
#define Ww   128
#define KK   5
#define HW   (Hh * Ww)

typedef _Float16 h4 __attribute__((ext_vector_type(4)));
typedef float    f4 __attribute__((ext_vector_type(4)));

// LDS layout (bytes):
//   x:    [0,     26112) : [6 rows][68 cols][32 j] f16 (spatial-major, j-minor)
//   kern: [26112, 32512) : [25 t][128 px] f16
//   w:    [32512, 58112) : [25 t][16 o][32 j] f16
// epilogue aliases x region as out-stage [16 o][132 px] f32.
#define XOFF 0
#define KOFF 26112
#define WOFF 32512
#define SMEMB 58112

// Block = 256 threads (4 waves) = 64x2 pixel tile, o-half (16 ch).
// Per tap t: partial_t[px][o] = sum_j x[j,px+t] * w[o,j,t] via 2x
// mfma_f32_16x16x16f16 (K-chained), then acc += kern[t][px] * partial_t.
__global__ __launch_bounds__(256, 2) void pac_mfma(
    const float* __restrict__ x, const float* __restrict__ guide,
    const float* __restrict__ weight, const float* __restrict__ bias,
    float* __restrict__ out)
{
    __shared__ __align__(16) unsigned char smem[SMEMB];

    const int tid  = threadIdx.x;
    const int bx   = blockIdx.x;           // 0..127 tiles
    const int half = blockIdx.y;           // 0..1 output half
    const int bz   = blockIdx.z;           // batch
    const int tileX = bx & 1, tileY = bx >> 1;
    const int tm = tileY * 2, tn = tileX * 64;

    // ---- stage x: 6x68 spatial slots x 8 j-quads, f16, zero-padded halo ----
    for (int it = 0; it < 13; ++it) {
        const int idx = tid + it * 256;            // b64 granule = 4 f16 (one j-quad)
        if (idx < 3264) {
            const int s = idx >> 3, q = idx & 7;   // slot, j-quad
            const int r = s / 68, c = s - r * 68;
            const int gm = tm + r - 2, gn = tn + c - 2;
            const bool ok = ((unsigned)gm < (unsigned)Hh) && ((unsigned)gn < (unsigned)Ww);
            const float* xp = x + ((size_t)(bz * CIN + q * 4)) * HW + gm * Ww + gn;
            h4 hv;
#pragma unroll
            for (int e = 0; e < 4; ++e)
                hv[e] = (_Float16)(ok ? xp[(size_t)e * HW] : 0.f);
            *(h4*)(smem + XOFF + (size_t)idx * 8) = hv;
        }
    }

    // ---- stage weights (o-half): w_lds[t][o][j] f16 ----
    for (int it = 0; it < 50; ++it) {
        const int idx = tid + it * 256;            // 12800 = 50*256 exactly
        const int t = idx >> 9, rem = idx & 511, o = rem >> 5, j = rem & 31;
        const float v = weight[((size_t)(half * 16 + o)) * (CIN * KK * KK) + j * (KK * KK) + t];
        *(_Float16*)(smem + WOFF + (size_t)idx * 2) = (_Float16)v;
    }

    // ---- adaptive kernel -> kern_lds[t][px] f16 (taps split across thread halves) ----
    {
        const int px = tid & 127, th = tid >> 7;   // waves 0-1: taps 0..12; waves 2-3: 13..24
        const int pr = px >> 6, pc = px & 63;
        const int m = tm + pr, n = tn + pc;
        const float* gb = guide + ((size_t)bz * CG) * HW + m * Ww + n;
        float center[CG];
#pragma unroll
        for (int c = 0; c < CG; ++c) center[c] = gb[c * HW];
        int t = 0;
#pragma unroll
        for (int k = 0; k < KK; ++k) {
            const int dm = k - 2;
            const bool rowok = ((unsigned)(m + dm) < (unsigned)Hh);
#pragma unroll
            for (int l = 0; l < KK; ++l) {
                if ((t < 13) == (th == 0)) {
                    const int dn = l - 2;
                    const bool ok = rowok && ((unsigned)(n + dn) < (unsigned)Ww);
                    float ss = 0.f;
#pragma unroll
                    for (int c = 0; c < CG; ++c) {
                        float gv = ok ? gb[c * HW + dm * Ww + dn] : 0.f;
                        float d = gv - center[c];
                        ss = fmaf(d, d, ss);
                    }
                    *(_Float16*)(smem + KOFF + ((size_t)t * 128 + px) * 2) =
                        (_Float16)__expf(-0.5f * ss);
                }
                ++t;
            }
        }
    }

    __syncthreads();

    // ---- main tap loop: MFMA over j, VALU scale by kern ----
    const int lane = tid & 63;
    const int l15 = lane & 15, kg = lane >> 4;
    const int wv = tid >> 6;
    const int st0 = wv * 32, st1 = st0 + 16;       // linear px bases (two 16-px subtiles)
    const int r0 = st0 >> 6, c0 = st0 & 63;        // both subtiles in same row

    f4 acc0 = {0.f, 0.f, 0.f, 0.f}, acc1 = {0.f, 0.f, 0.f, 0.f};
    const float bv = bias[half * 16 + l15];

    int t = 0;
#pragma unroll
    for (int k = 0; k < KK; ++k) {
        const int dm = k - 2;
#pragma unroll
        for (int l = 0; l < KK; ++l) {
            const int dn = l - 2;
            const int tb = WOFF + t * 1024;
            // B fragments: w_lds[t][o=l15][j = kg*4 (+16)]
            h4 Blo = *(const h4*)(smem + tb + l15 * 64 + kg * 8);
            h4 Bhi = *(const h4*)(smem + tb + l15 * 64 + 32 + kg * 8);
            // A fragments: x_lds[(r0+2+dm)][c + 2 + dn + l15][j = kg*4 (+16)]
            const int arow = (r0 + 2 + dm) * 68;
            const int a0 = XOFF + (arow + c0 + 2 + dn + l15) * 64 + kg * 8;
            const int a1 = XOFF + (arow + c0 + 18 + dn + l15) * 64 + kg * 8;   // +16 px
            h4 A0lo = *(const h4*)(smem + a0);
            h4 A0hi = *(const h4*)(smem + a0 + 32);
            h4 A1lo = *(const h4*)(smem + a1);
            h4 A1hi = *(const h4*)(smem + a1 + 32);

            f4 c0v = __builtin_amdgcn_mfma_f32_16x16x16f16(A0lo, Blo, (f4){0.f,0.f,0.f,0.f}, 0, 0, 0);
            c0v    = __builtin_amdgcn_mfma_f32_16x16x16f16(A0hi, Bhi, c0v, 0, 0, 0);
            f4 c1v = __builtin_amdgcn_mfma_f32_16x16x16f16(A1lo, Blo, (f4){0.f,0.f,0.f,0.f}, 0, 0, 0);
            c1v    = __builtin_amdgcn_mfma_f32_16x16x16f16(A1hi, Bhi, c1v, 0, 0, 0);

            // kern[t][px] for this lane's 4 C-rows (px = st + kg*4 + i)
            h4 k0 = *(const h4*)(smem + KOFF + t * 256 + (st0 + kg * 4) * 2);
            h4 k1 = *(const h4*)(smem + KOFF + t * 256 + (st1 + kg * 4) * 2);
#pragma unroll
            for (int i = 0; i < 4; ++i) {
                acc0[i] = fmaf((float)k0[i], c0v[i], acc0[i]);
                acc1[i] = fmaf((float)k1[i], c1v[i], acc1[i]);
            }
            ++t;
        }
    }

#pragma unroll
    for (int i = 0; i < 4; ++i) { acc0[i] += bv; acc1[i] += bv; }

    // ---- transpose through LDS for dense stores ----
    __syncthreads();
    float* outst = (float*)smem;                    // [16 o][132 px] f32, aliases x region
    *(f4*)(outst + l15 * 132 + st0 + kg * 4) = acc0;
    *(f4*)(outst + l15 * 132 + st1 + kg * 4) = acc1;
    __syncthreads();

    const int o = tid >> 4, p4 = (tid & 15) * 4;    // lanes 0-15 share o -> 256B dense stores
    float* op = out + ((size_t)(bz * COUT + half * 16 + o)) * HW;
    f4 v0 = *(const f4*)(outst + o * 132 + p4);
    f4 v1 = *(const f4*)(outst + o * 132 + p4 + 64);
    *(f4*)(op + (size_t)tm * Ww + tn + p4) = v0;
    *(f4*)(op + (size_t)(tm + 1) * Ww + tn + p4) = v1;
}

extern "C" void kernel_launch(void* const* d_in, const int* in_sizes, int n_in,
                              void* d_out, int out_size, void* d_ws, size_t ws_size,
                              hipStream_t stream) {
    const float* x      = (const float*)d_in[0];
    const float* guide  = (const float*)d_in[1];
    const float* weight = (const float*)d_in[2];
    const float* bias   = (const float*)d_in[3];
    float* out = (float*)d_out;

    dim3 grid(128, 2, Bn);   // 128 spatial tiles (64x2) * 2 o-halves * 4 batches
    pac_mfma<<<grid, dim3(256), 0, stream>>>(x, guide, weight, bias, out);
}

// Round 6
// 31.411 us; speedup vs baseline: 5.4637x; 3.3889x over previous
//
#include <hip/hip_runtime.h>

#define Bn   4
#define CIN  32
#define COUT 32
#define CG   8
#define Hh   128
#define Ww   128
#define KK   5
#define HW   (Hh * Ww)

#define TW   64     // tile 64 wide x 4 tall = 256 px per block
#define TH   4
#define PRW  68     // halo 68 x 8
#define PRH  8
#define NSLOT (PRW * PRH)   // 544

typedef _Float16 h8  __attribute__((ext_vector_type(8)));
typedef _Float16 h4v __attribute__((ext_vector_type(4)));
typedef float    f4  __attribute__((ext_vector_type(4)));

// LDS layout (bytes) — SoA over j-octets so fragment reads have 16B lane
// stride (banks l*4%32 -> conflict-free b128):
//   x:    [4 jg][544 slots] h8            : 34816
//   w:    [25 t][4 jg][16 o] h8           : 25600
//   kern: [25 t][256 px] f16              : 12800
// epilogue aliases x region as [16 o][260 px] f32 (16640 B).
#define XOFF  0
#define XJG   8704           // 544*16 bytes per j-group plane
#define WOFF  34816
#define KOFF  60416
#define SMEMB 73216

__global__ __launch_bounds__(512, 4) void pac_mfma2(
    const float* __restrict__ x, const float* __restrict__ guide,
    const float* __restrict__ weight, const float* __restrict__ bias,
    float* __restrict__ out)
{
    __shared__ __align__(16) unsigned char smem[SMEMB];

    const int tid  = threadIdx.x;
    const int bx   = blockIdx.x;       // 0..63 spatial tiles (2 wide x 32 tall)
    const int half = blockIdx.y;       // 0..1 output half (16 ch)
    const int bz   = blockIdx.z;       // batch
    const int tm = (bx >> 1) * TH;
    const int tn = (bx & 1) * TW;

    // ---- stage x: 32 j x 544 slots, coalesced global (lane -> consecutive col) ----
    const float* xb = x + (size_t)bz * CIN * HW;
#pragma unroll
    for (int it = 0; it < 34; ++it) {            // 34*512 = 17408 = 32*544 exact
        const int idx  = it * 512 + tid;
        const int j    = idx / NSLOT;
        const int slot = idx - j * NSLOT;
        const int r    = slot / PRW;
        const int c    = slot - r * PRW;
        const int gm = tm + r - 2, gn = tn + c - 2;
        float v = 0.f;
        if ((unsigned)gm < (unsigned)Hh && (unsigned)gn < (unsigned)Ww)
            v = xb[(size_t)j * HW + gm * Ww + gn];
        *(_Float16*)(smem + XOFF + (j >> 3) * XJG + slot * 16 + (j & 7) * 2) = (_Float16)v;
    }

    // ---- stage w (o-half): w_lds[t][jg][o][e] = w[half*16+o][jg*8+e][t] ----
#pragma unroll
    for (int it = 0; it < 25; ++it) {            // 25*512 = 12800 exact
        const int idx = it * 512 + tid;
        const int o = idx & 15;
        const int j = (idx >> 4) & 31;
        const int t = idx >> 9;
        const float v = weight[(size_t)(half * 16 + o) * (CIN * KK * KK) + j * (KK * KK) + t];
        *(_Float16*)(smem + WOFF + t * 1024 + (j >> 3) * 256 + o * 16 + (j & 7) * 2) = (_Float16)v;
    }

    // ---- adaptive kernel -> kern_lds[t][px] f16 (tap set split across thread halves) ----
    {
        const int px = tid & 255, th = tid >> 8;   // th=0: taps 0..12, th=1: taps 13..24
        const int pr = px >> 6, pc = px & 63;
        const int m = tm + pr, n = tn + pc;
        const float* gb = guide + ((size_t)bz * CG) * HW + m * Ww + n;
        float center[CG];
#pragma unroll
        for (int c = 0; c < CG; ++c) center[c] = gb[c * HW];
        int t = 0;
#pragma unroll
        for (int k = 0; k < KK; ++k) {
            const int dm = k - 2;
            const bool rowok = ((unsigned)(m + dm) < (unsigned)Hh);
#pragma unroll
            for (int l = 0; l < KK; ++l) {
                if ((t < 13) == (th == 0)) {
                    const int dn = l - 2;
                    const bool ok = rowok && ((unsigned)(n + dn) < (unsigned)Ww);
                    float ss = 0.f;
#pragma unroll
                    for (int c = 0; c < CG; ++c) {
                        float gv = ok ? gb[c * HW + dm * Ww + dn] : 0.f;
                        float d = gv - center[c];
                        ss = fmaf(d, d, ss);
                    }
                    *(_Float16*)(smem + KOFF + t * 512 + px * 2) = (_Float16)__expf(-0.5f * ss);
                }
                ++t;
            }
        }
    }

    __syncthreads();

    // ---- main loop: per tap, 2x mfma_f32_16x16x32_f16 (full K=Cin) + kern scale ----
    const int lane = tid & 63;
    const int l15 = lane & 15, kg = lane >> 4;
    const int wv = tid >> 6;                   // 8 waves
    const int st0 = wv * 32, st1 = st0 + 16;   // two 16-px M-subtiles (same row)
    const int r0 = wv >> 1;                    // tile row 0..3
    const int c00 = (wv & 1) * 32;             // col base 0/32

    f4 acc0 = {0.f, 0.f, 0.f, 0.f}, acc1 = {0.f, 0.f, 0.f, 0.f};
    const unsigned char* xg = smem + XOFF + kg * XJG;
    const float bv = bias[half * 16 + l15];

    int t = 0;
#pragma unroll
    for (int k = 0; k < KK; ++k) {
#pragma unroll
        for (int l = 0; l < KK; ++l) {
            // A: x_lds[kg][(r0+k)*68 + c00 + l + l15]  (halo +2 cancels dm=k-2)
            const int abase = ((r0 + k) * PRW + c00 + l + l15) * 16;
            h8 A0 = *(const h8*)(xg + abase);
            h8 A1 = *(const h8*)(xg + abase + 256);        // +16 cols
            h8 Bv = *(const h8*)(smem + WOFF + t * 1024 + kg * 256 + l15 * 16);

            f4 p0 = __builtin_amdgcn_mfma_f32_16x16x32_f16(A0, Bv, (f4){0.f,0.f,0.f,0.f}, 0, 0, 0);
            f4 p1 = __builtin_amdgcn_mfma_f32_16x16x32_f16(A1, Bv, (f4){0.f,0.f,0.f,0.f}, 0, 0, 0);

            h4v k0 = *(const h4v*)(smem + KOFF + t * 512 + (st0 + kg * 4) * 2);
            h4v k1 = *(const h4v*)(smem + KOFF + t * 512 + (st1 + kg * 4) * 2);
#pragma unroll
            for (int i = 0; i < 4; ++i) {
                acc0[i] = fmaf((float)k0[i], p0[i], acc0[i]);
                acc1[i] = fmaf((float)k1[i], p1[i], acc1[i]);
            }
            ++t;
        }
    }

#pragma unroll
    for (int i = 0; i < 4; ++i) { acc0[i] += bv; acc1[i] += bv; }

    // ---- transpose through LDS (aliases x region) for dense 32B stores ----
    __syncthreads();
    float* outst = (float*)smem;               // [16 o][260 px]
    *(f4*)(outst + l15 * 260 + st0 + kg * 4) = acc0;
    *(f4*)(outst + l15 * 260 + st1 + kg * 4) = acc1;
    __syncthreads();

    const int o = tid >> 5;                    // 0..15
    const int p = (tid & 31) * 8;              // 0..248
    f4 v0 = *(const f4*)(outst + o * 260 + p);
    f4 v1 = *(const f4*)(outst + o * 260 + p + 4);
    const int mr = p >> 6, nc = p & 63;
    float* op = out + ((size_t)(bz * COUT + half * 16 + o)) * HW + (size_t)(tm + mr) * Ww + tn + nc;
    *(f4*)op = v0;
    *(f4*)(op + 4) = v1;
}

extern "C" void kernel_launch(void* const* d_in, const int* in_sizes, int n_in,
                              void* d_out, int out_size, void* d_ws, size_t ws_size,
                              hipStream_t stream) {
    const float* x      = (const float*)d_in[0];
    const float* guide  = (const float*)d_in[1];
    const float* weight = (const float*)d_in[2];
    const float* bias   = (const float*)d_in[3];
    float* out = (float*)d_out;

    dim3 grid(64, 2, Bn);   // 512 blocks of 512 threads -> exactly 2 blocks/CU, one round
    pac_mfma2<<<grid, dim3(512), 0, stream>>>(x, guide, weight, bias, out);
}

// Round 7
// 27.888 us; speedup vs baseline: 6.1538x; 1.1263x over previous
//
#include <hip/hip_runtime.h>

#define Bn   4
#define CIN  32
#define COUT 32
#define CG   8
#define Hh   128
#define Ww   128
#define KK   5
#define HW   (Hh * Ww)

#define TW   64     // tile 64 wide x 4 tall = 256 px per block
#define TH   4
#define PRW  68     // halo 68 x 8
#define PRH  8
#define NSLOT (PRW * PRH)   // 544

typedef _Float16 h8  __attribute__((ext_vector_type(8)));
typedef _Float16 h4v __attribute__((ext_vector_type(4)));
typedef float    f4  __attribute__((ext_vector_type(4)));

// LDS layout (bytes) — SoA over j-octets: fragment reads have 16B lane stride.
//   x:    [4 jg][544 slots] h8            : 34816
//   w:    [25 t][4 jg][16 o] h8           : 25600
//   kern: [25 t][256 px] f16              : 12800
#define XOFF  0
#define XJG   8704           // 544*16 B per j-group plane (= 68*128, bank-congruent)
#define WOFF  34816
#define KOFF  60416
#define SMEMB 73216

// workspace offsets (bytes)
#define XT_OFF 0
#define GT_OFF 4194304
#define WT_OFF 5242880
#define WS_NEED (5242880 + 51200)

// ---------- pre-transpose kernels (memory-bound, run once per call) ----------
__global__ void transpose_x(const float* __restrict__ x, _Float16* __restrict__ xt) {
    const int m = blockIdx.x, b = blockIdx.y;
    const int n = threadIdx.x & 127, jh = threadIdx.x >> 7;   // jh: channel half
    const float* xp = x + ((size_t)(b * CIN + jh * 16)) * HW + m * Ww + n;
    h8 v0, v1;
#pragma unroll
    for (int e = 0; e < 8; ++e) {
        v0[e] = (_Float16)xp[(size_t)e * HW];
        v1[e] = (_Float16)xp[(size_t)(e + 8) * HW];
    }
    h8* dst = (h8*)xt + ((size_t)b * HW + m * Ww + n) * 4 + jh * 2;
    dst[0] = v0; dst[1] = v1;
}

__global__ void transpose_g(const float* __restrict__ g, _Float16* __restrict__ gt) {
    const int m = blockIdx.x * 2 + (threadIdx.x >> 7), b = blockIdx.y;
    const int n = threadIdx.x & 127;
    const float* gp = g + (size_t)b * CG * HW + m * Ww + n;
    h8 v;
#pragma unroll
    for (int e = 0; e < 8; ++e) v[e] = (_Float16)gp[(size_t)e * HW];
    ((h8*)gt)[(size_t)b * HW + m * Ww + n] = v;
}

__global__ void transpose_w(const float* __restrict__ w, _Float16* __restrict__ wt) {
    const int idx = blockIdx.x * 512 + threadIdx.x;     // 0..25599
    const int ht = idx >> 9;                            // 0..49
    const int half = ht / 25, t = ht - half * 25;
    const int rem = idx & 511;
    const int jg = rem >> 7, o = (rem >> 3) & 15, e = rem & 7;
    wt[idx] = (_Float16)w[(size_t)(half * 16 + o) * (CIN * KK * KK) + (jg * 8 + e) * (KK * KK) + t];
}

// ---------- main kernel: all-f16 staging, MFMA tap loop ----------
__global__ __launch_bounds__(512, 4) void pac_mfma3(
    const _Float16* __restrict__ xt, const _Float16* __restrict__ gt,
    const _Float16* __restrict__ wt, const float* __restrict__ bias,
    float* __restrict__ out)
{
    __shared__ __align__(16) unsigned char smem[SMEMB];

    const int tid  = threadIdx.x;
    const int bx   = blockIdx.x;       // 0..63 spatial tiles (2 wide x 32 tall)
    const int half = blockIdx.y;       // 0..1 output half (16 ch)
    const int bz   = blockIdx.z;       // batch
    const int tm = (bx >> 1) * TH;
    const int tn = (bx & 1) * TW;

    // ---- stage x: 544 slots x 4 j-octets, b128 in / b128 out ----
    const int pxbase = bz * HW;
#pragma unroll
    for (int it = 0; it < 5; ++it) {
        const int idx = it * 512 + tid;            // over 2176 = 544*4
        if (idx < 2176) {
            const int slot = idx >> 2, jg = idx & 3;
            const int r = slot / PRW;
            const int c = slot - r * PRW;
            const int gm = tm + r - 2, gn = tn + c - 2;
            h8 v = {};
            if ((unsigned)gm < (unsigned)Hh && (unsigned)gn < (unsigned)Ww)
                v = *(const h8*)(xt + ((size_t)(pxbase + gm * Ww + gn)) * 32 + jg * 8);
            *(h8*)(smem + XOFF + jg * XJG + slot * 16) = v;
        }
    }

    // ---- stage w (o-half): linear b128 copy, already in LDS image layout ----
    const h8* wth = (const h8*)(wt + half * 12800);
#pragma unroll
    for (int it = 0; it < 4; ++it) {
        const int idx = it * 512 + tid;            // over 1600 h8
        if (idx < 1600)
            *(h8*)(smem + WOFF + idx * 16) = wth[idx];
    }

    // ---- adaptive kernel from f16 guide_t (global/L1, no guide staging) ----
    {
        const int px = tid & 255, th = tid >> 8;   // th=0: taps 0..12, th=1: 13..24
        const int pr = px >> 6, pc = px & 63;
        const int m = tm + pr, n = tn + pc;
        const h8* gtb = (const h8*)gt + (size_t)bz * HW;
        const h8 g0 = gtb[m * Ww + n];
        float cg[8];
#pragma unroll
        for (int c = 0; c < 8; ++c) cg[c] = (float)g0[c];
        int t = 0;
#pragma unroll
        for (int k = 0; k < KK; ++k) {
#pragma unroll
            for (int l = 0; l < KK; ++l) {
                if ((t < 13) == (th == 0)) {
                    const int gm = m + k - 2, gn = n + l - 2;
                    h8 gv = {};
                    if ((unsigned)gm < (unsigned)Hh && (unsigned)gn < (unsigned)Ww)
                        gv = gtb[gm * Ww + gn];
                    float ss = 0.f;
#pragma unroll
                    for (int i = 0; i < 8; ++i) {
                        const float d = (float)gv[i] - cg[i];
                        ss = fmaf(d, d, ss);
                    }
                    *(_Float16*)(smem + KOFF + t * 512 + px * 2) = (_Float16)__expf(-0.5f * ss);
                }
                ++t;
            }
        }
    }

    __syncthreads();

    // ---- main loop: per tap, 2x mfma_f32_16x16x32_f16 (K=Cin) + kern scale ----
    const int lane = tid & 63;
    const int l15 = lane & 15, kg = lane >> 4;
    const int wv = tid >> 6;                   // 8 waves
    const int st0 = wv * 32, st1 = st0 + 16;   // two 16-px M-subtiles (same row)
    const int r0 = wv >> 1;                    // tile row 0..3
    const int c00 = (wv & 1) * 32;             // col base 0/32

    f4 acc0 = {0.f, 0.f, 0.f, 0.f}, acc1 = {0.f, 0.f, 0.f, 0.f};
    const unsigned char* xg = smem + XOFF + kg * XJG;
    const float bv = bias[half * 16 + l15];

    int t = 0;
#pragma unroll
    for (int k = 0; k < KK; ++k) {
#pragma unroll
        for (int l = 0; l < KK; ++l) {
            const int abase = ((r0 + k) * PRW + c00 + l + l15) * 16;
            h8 A0 = *(const h8*)(xg + abase);
            h8 A1 = *(const h8*)(xg + abase + 256);        // +16 cols
            h8 Bv = *(const h8*)(smem + WOFF + t * 1024 + kg * 256 + l15 * 16);

            f4 p0 = __builtin_amdgcn_mfma_f32_16x16x32_f16(A0, Bv, (f4){0.f,0.f,0.f,0.f}, 0, 0, 0);
            f4 p1 = __builtin_amdgcn_mfma_f32_16x16x32_f16(A1, Bv, (f4){0.f,0.f,0.f,0.f}, 0, 0, 0);

            h4v k0 = *(const h4v*)(smem + KOFF + t * 512 + (st0 + kg * 4) * 2);
            h4v k1 = *(const h4v*)(smem + KOFF + t * 512 + (st1 + kg * 4) * 2);
#pragma unroll
            for (int i = 0; i < 4; ++i) {
                acc0[i] = fmaf((float)k0[i], p0[i], acc0[i]);
                acc1[i] = fmaf((float)k1[i], p1[i], acc1[i]);
            }
            ++t;
        }
    }

#pragma unroll
    for (int i = 0; i < 4; ++i) { acc0[i] += bv; acc1[i] += bv; }

    // ---- transpose through LDS (aliases x region) for dense stores ----
    __syncthreads();
    float* outst = (float*)smem;               // [16 o][260 px]
    *(f4*)(outst + l15 * 260 + st0 + kg * 4) = acc0;
    *(f4*)(outst + l15 * 260 + st1 + kg * 4) = acc1;
    __syncthreads();

    const int o = tid >> 5;                    // 0..15
    const int p = (tid & 31) * 8;              // 0..248
    f4 v0 = *(const f4*)(outst + o * 260 + p);
    f4 v1 = *(const f4*)(outst + o * 260 + p + 4);
    const int mr = p >> 6, nc = p & 63;
    float* op = out + ((size_t)(bz * COUT + half * 16 + o)) * HW + (size_t)(tm + mr) * Ww + tn + nc;
    *(f4*)op = v0;
    *(f4*)(op + 4) = v1;
}

// ---------- fallback (R6 kernel, used only if ws_size too small) ----------
__global__ __launch_bounds__(512, 4) void pac_mfma2(
    const float* __restrict__ x, const float* __restrict__ guide,
    const float* __restrict__ weight, const float* __restrict__ bias,
    float* __restrict__ out)
{
    __shared__ __align__(16) unsigned char smem[SMEMB];
    const int tid  = threadIdx.x;
    const int bx   = blockIdx.x;
    const int half = blockIdx.y;
    const int bz   = blockIdx.z;
    const int tm = (bx >> 1) * TH;
    const int tn = (bx & 1) * TW;

    const float* xb = x + (size_t)bz * CIN * HW;
#pragma unroll
    for (int it = 0; it < 34; ++it) {
        const int idx  = it * 512 + tid;
        const int j    = idx / NSLOT;
        const int slot = idx - j * NSLOT;
        const int r    = slot / PRW;
        const int c    = slot - r * PRW;
        const int gm = tm + r - 2, gn = tn + c - 2;
        float v = 0.f;
        if ((unsigned)gm < (unsigned)Hh && (unsigned)gn < (unsigned)Ww)
            v = xb[(size_t)j * HW + gm * Ww + gn];
        *(_Float16*)(smem + XOFF + (j >> 3) * XJG + slot * 16 + (j & 7) * 2) = (_Float16)v;
    }
#pragma unroll
    for (int it = 0; it < 25; ++it) {
        const int idx = it * 512 + tid;
        const int o = idx & 15;
        const int j = (idx >> 4) & 31;
        const int t = idx >> 9;
        const float v = weight[(size_t)(half * 16 + o) * (CIN * KK * KK) + j * (KK * KK) + t];
        *(_Float16*)(smem + WOFF + t * 1024 + (j >> 3) * 256 + o * 16 + (j & 7) * 2) = (_Float16)v;
    }
    {
        const int px = tid & 255, th = tid >> 8;
        const int pr = px >> 6, pc = px & 63;
        const int m = tm + pr, n = tn + pc;
        const float* gb = guide + ((size_t)bz * CG) * HW + m * Ww + n;
        float center[CG];
#pragma unroll
        for (int c = 0; c < CG; ++c) center[c] = gb[c * HW];
        int t = 0;
#pragma unroll
        for (int k = 0; k < KK; ++k) {
            const int dm = k - 2;
            const bool rowok = ((unsigned)(m + dm) < (unsigned)Hh);
#pragma unroll
            for (int l = 0; l < KK; ++l) {
                if ((t < 13) == (th == 0)) {
                    const int dn = l - 2;
                    const bool ok = rowok && ((unsigned)(n + dn) < (unsigned)Ww);
                    float ss = 0.f;
#pragma unroll
                    for (int c = 0; c < CG; ++c) {
                        float gv = ok ? gb[c * HW + dm * Ww + dn] : 0.f;
                        float d = gv - center[c];
                        ss = fmaf(d, d, ss);
                    }
                    *(_Float16*)(smem + KOFF + t * 512 + px * 2) = (_Float16)__expf(-0.5f * ss);
                }
                ++t;
            }
        }
    }
    __syncthreads();
    const int lane = tid & 63;
    const int l15 = lane & 15, kg = lane >> 4;
    const int wv = tid >> 6;
    const int st0 = wv * 32, st1 = st0 + 16;
    const int r0 = wv >> 1;
    const int c00 = (wv & 1) * 32;
    f4 acc0 = {0.f, 0.f, 0.f, 0.f}, acc1 = {0.f, 0.f, 0.f, 0.f};
    const unsigned char* xg = smem + XOFF + kg * XJG;
    const float bv = bias[half * 16 + l15];
    int t = 0;
#pragma unroll
    for (int k = 0; k < KK; ++k) {
#pragma unroll
        for (int l = 0; l < KK; ++l) {
            const int abase = ((r0 + k) * PRW + c00 + l + l15) * 16;
            h8 A0 = *(const h8*)(xg + abase);
            h8 A1 = *(const h8*)(xg + abase + 256);
            h8 Bv = *(const h8*)(smem + WOFF + t * 1024 + kg * 256 + l15 * 16);
            f4 p0 = __builtin_amdgcn_mfma_f32_16x16x32_f16(A0, Bv, (f4){0.f,0.f,0.f,0.f}, 0, 0, 0);
            f4 p1 = __builtin_amdgcn_mfma_f32_16x16x32_f16(A1, Bv, (f4){0.f,0.f,0.f,0.f}, 0, 0, 0);
            h4v k0 = *(const h4v*)(smem + KOFF + t * 512 + (st0 + kg * 4) * 2);
            h4v k1 = *(const h4v*)(smem + KOFF + t * 512 + (st1 + kg * 4) * 2);
#pragma unroll
            for (int i = 0; i < 4; ++i) {
                acc0[i] = fmaf((float)k0[i], p0[i], acc0[i]);
                acc1[i] = fmaf((float)k1[i], p1[i], acc1[i]);
            }
            ++t;
        }
    }
#pragma unroll
    for (int i = 0; i < 4; ++i) { acc0[i] += bv; acc1[i] += bv; }
    __syncthreads();
    float* outst = (float*)smem;
    *(f4*)(outst + l15 * 260 + st0 + kg * 4) = acc0;
    *(f4*)(outst + l15 * 260 + st1 + kg * 4) = acc1;
    __syncthreads();
    const int o = tid >> 5;
    const int p = (tid & 31) * 8;
    f4 v0 = *(const f4*)(outst + o * 260 + p);
    f4 v1 = *(const f4*)(outst + o * 260 + p + 4);
    const int mr = p >> 6, nc = p & 63;
    float* op = out + ((size_t)(bz * COUT + half * 16 + o)) * HW + (size_t)(tm + mr) * Ww + tn + nc;
    *(f4*)op = v0;
    *(f4*)(op + 4) = v1;
}

extern "C" void kernel_launch(void* const* d_in, const int* in_sizes, int n_in,
                              void* d_out, int out_size, void* d_ws, size_t ws_size,
                              hipStream_t stream) {
    const float* x      = (const float*)d_in[0];
    const float* guide  = (const float*)d_in[1];
    const float* weight = (const float*)d_in[2];
    const float* bias   = (const float*)d_in[3];
    float* out = (float*)d_out;

    if (ws_size >= (size_t)WS_NEED) {
        _Float16* xt = (_Float16*)((char*)d_ws + XT_OFF);
        _Float16* gt = (_Float16*)((char*)d_ws + GT_OFF);
        _Float16* wt = (_Float16*)((char*)d_ws + WT_OFF);
        transpose_x<<<dim3(Hh, Bn), 256, 0, stream>>>(x, xt);
        transpose_g<<<dim3(Hh / 2, Bn), 256, 0, stream>>>(guide, gt);
        transpose_w<<<dim3(50), 512, 0, stream>>>(weight, wt);
        pac_mfma3<<<dim3(64, 2, Bn), 512, 0, stream>>>(xt, gt, wt, bias, out);
    } else {
        pac_mfma2<<<dim3(64, 2, Bn), 512, 0, stream>>>(x, guide, weight, bias, out);
    }
}

// Round 8
// 24.755 us; speedup vs baseline: 6.9327x; 1.1266x over previous
//
#include <hip/hip_runtime.h>

#define Bn   4
#define CIN  32
#define COUT 32
#define CG   8
#define Hh   128
#define Ww   128
#define KK   5
#define HW   (Hh * Ww)

#define TW   64     // tile 64 wide x 4 tall = 256 px per block
#define TH   4
#define PRW  68     // halo 68 x 8
#define PRH  8
#define NSLOT (PRW * PRH)   // 544

typedef _Float16 h8  __attribute__((ext_vector_type(8)));
typedef _Float16 h4v __attribute__((ext_vector_type(4)));
typedef float    f4  __attribute__((ext_vector_type(4)));

// LDS layout (bytes) — SoA over j-octets: fragment reads have 16B lane stride.
//   x:    [4 jg][544 slots] h8            : 34816
//   w:    [25 t][4 jg][16 o] h8           : 25600
//   kern: [25 t][256 px] f16              : 12800
#define XOFF  0
#define XJG   8704
#define WOFF  34816
#define KOFF  60416
#define SMEMB 73216

// workspace (bytes)
#define XT_OFF 0                       // 4*16384*32*2 = 4,194,304
#define WT_OFF 4194304                 // 25600*2      =    51,200
#define KW_OFF 4245504                 // 4*64*25*256*2 = 3,276,800
#define WS_NEED 7522304

// ---------- fused pre-pass: x/w transpose + kern tiles (1 dispatch) ----------
__global__ __launch_bounds__(512) void prep(
    const float* __restrict__ x, const float* __restrict__ guide,
    const float* __restrict__ w,
    _Float16* __restrict__ xt, _Float16* __restrict__ wt, _Float16* __restrict__ kw)
{
    const int bid = blockIdx.x;
    const int tid = threadIdx.x;

    if (bid < 512) {
        // ---- region X: x[b][j][m][n] f32 -> xt[b][m][n][32j] f16 ----
        const int b = bid >> 7, m = bid & 127;
        const int n = tid & 127, jh = tid >> 7;       // jh = j-octet 0..3
        const float* xp = x + ((size_t)(b * CIN + jh * 8)) * HW + m * Ww + n;
        h8 v;
#pragma unroll
        for (int e = 0; e < 8; ++e) v[e] = (_Float16)xp[(size_t)e * HW];
        ((h8*)xt)[((size_t)b * HW + m * Ww + n) * 4 + jh] = v;
    } else if (bid < 562) {
        // ---- region W: w -> wt[half][t][jg][o][e] f16 (LDS image) ----
        const int idx = (bid - 512) * 512 + tid;      // 0..25599
        const int ht = idx >> 9;
        const int half = ht / 25, t = ht - half * 25;
        const int rem = idx & 511;
        const int jg = rem >> 7, o = (rem >> 3) & 15, e = rem & 7;
        wt[idx] = (_Float16)w[(size_t)(half * 16 + o) * (CIN * KK * KK) + (jg * 8 + e) * (KK * KK) + t];
    } else {
        // ---- region K: adaptive kernel per 64x4 tile -> kw[b][tile][t][256px] f16 ----
        __shared__ __align__(16) _Float16 gl[NSLOT * 8];   // [slot][8c] h8, 8704 B
        const int tb = bid - 562;                     // 0..255
        const int tile = tb & 63, b = tb >> 6;
        const int tm = (tile >> 1) * TH, tn = (tile & 1) * TW;
        const float* gb = guide + (size_t)b * CG * HW;
#pragma unroll
        for (int it = 0; it < 2; ++it) {
            const int slot = it * 512 + tid;
            if (slot < NSLOT) {
                const int r = slot / PRW, c = slot - r * PRW;
                const int gm = tm + r - 2, gn = tn + c - 2;
                h8 v = {};
                if ((unsigned)gm < (unsigned)Hh && (unsigned)gn < (unsigned)Ww) {
#pragma unroll
                    for (int cg = 0; cg < 8; ++cg)
                        v[cg] = (_Float16)gb[(size_t)cg * HW + gm * Ww + gn];
                }
                *(h8*)(gl + slot * 8) = v;
            }
        }
        __syncthreads();
        const int px = tid & 255, th = tid >> 8;      // th=0: taps 0..12, th=1: 13..24
        const int pr = px >> 6, pc = px & 63;
        const h8 c8 = *(const h8*)(gl + ((pr + 2) * PRW + pc + 2) * 8);
        float cg[8];
#pragma unroll
        for (int i = 0; i < 8; ++i) cg[i] = (float)c8[i];
        _Float16* kout = kw + ((size_t)(b * 64 + tile) * 25) * 256;
        int t = 0;
#pragma unroll
        for (int k = 0; k < KK; ++k) {
#pragma unroll
            for (int l = 0; l < KK; ++l) {
                if ((t < 13) == (th == 0)) {
                    const h8 gv = *(const h8*)(gl + ((pr + k) * PRW + pc + l) * 8);
                    float ss = 0.f;
#pragma unroll
                    for (int i = 0; i < 8; ++i) {
                        const float d = (float)gv[i] - cg[i];
                        ss = fmaf(d, d, ss);
                    }
                    kout[t * 256 + px] = (_Float16)__expf(-0.5f * ss);
                }
                ++t;
            }
        }
    }
}

// ---------- main kernel: pure-copy staging, MFMA tap loop ----------
__global__ __launch_bounds__(512, 4) void pac_mfma4(
    const _Float16* __restrict__ xt, const _Float16* __restrict__ wt,
    const _Float16* __restrict__ kw, const float* __restrict__ bias,
    float* __restrict__ out)
{
    __shared__ __align__(16) unsigned char smem[SMEMB];

    const int tid  = threadIdx.x;
    const int bx   = blockIdx.x;       // 0..63 spatial tiles (2 wide x 32 tall)
    const int half = blockIdx.y;       // 0..1 output half (16 ch)
    const int bz   = blockIdx.z;       // batch
    const int tm = (bx >> 1) * TH;
    const int tn = (bx & 1) * TW;

    // ---- stage x: 544 slots x 4 j-octets, b128 in / b128 out ----
    const int pxbase = bz * HW;
#pragma unroll
    for (int it = 0; it < 5; ++it) {
        const int idx = it * 512 + tid;            // over 2176 = 544*4
        if (idx < 2176) {
            const int slot = idx >> 2, jg = idx & 3;
            const int r = slot / PRW;
            const int c = slot - r * PRW;
            const int gm = tm + r - 2, gn = tn + c - 2;
            h8 v = {};
            if ((unsigned)gm < (unsigned)Hh && (unsigned)gn < (unsigned)Ww)
                v = *(const h8*)(xt + ((size_t)(pxbase + gm * Ww + gn)) * 32 + jg * 8);
            *(h8*)(smem + XOFF + jg * XJG + slot * 16) = v;
        }
    }

    // ---- stage w (o-half): linear b128 copy ----
    const h8* wth = (const h8*)(wt + half * 12800);
#pragma unroll
    for (int it = 0; it < 4; ++it) {
        const int idx = it * 512 + tid;            // over 1600 h8
        if (idx < 1600)
            *(h8*)(smem + WOFF + idx * 16) = wth[idx];
    }

    // ---- stage kern: linear b128 copy of this tile's 25x256 f16 ----
    const h8* ksrc = (const h8*)(kw + ((size_t)(bz * 64 + bx) * 25) * 256);
#pragma unroll
    for (int it = 0; it < 2; ++it) {
        const int idx = it * 512 + tid;            // over 800 h8
        if (idx < 800)
            *(h8*)(smem + KOFF + idx * 16) = ksrc[idx];
    }

    __syncthreads();

    // ---- main loop: per tap, 2x mfma_f32_16x16x32_f16 (K=Cin) + kern scale ----
    const int lane = tid & 63;
    const int l15 = lane & 15, kg = lane >> 4;
    const int wv = tid >> 6;                   // 8 waves
    const int st0 = wv * 32, st1 = st0 + 16;   // two 16-px M-subtiles (same row)
    const int r0 = wv >> 1;                    // tile row 0..3
    const int c00 = (wv & 1) * 32;             // col base 0/32

    f4 acc0 = {0.f, 0.f, 0.f, 0.f}, acc1 = {0.f, 0.f, 0.f, 0.f};
    const unsigned char* xg = smem + XOFF + kg * XJG;
    const float bv = bias[half * 16 + l15];

    int t = 0;
#pragma unroll
    for (int k = 0; k < KK; ++k) {
#pragma unroll
        for (int l = 0; l < KK; ++l) {
            const int abase = ((r0 + k) * PRW + c00 + l + l15) * 16;
            h8 A0 = *(const h8*)(xg + abase);
            h8 A1 = *(const h8*)(xg + abase + 256);        // +16 cols
            h8 Bv = *(const h8*)(smem + WOFF + t * 1024 + kg * 256 + l15 * 16);

            f4 p0 = __builtin_amdgcn_mfma_f32_16x16x32_f16(A0, Bv, (f4){0.f,0.f,0.f,0.f}, 0, 0, 0);
            f4 p1 = __builtin_amdgcn_mfma_f32_16x16x32_f16(A1, Bv, (f4){0.f,0.f,0.f,0.f}, 0, 0, 0);

            h4v k0 = *(const h4v*)(smem + KOFF + t * 512 + (st0 + kg * 4) * 2);
            h4v k1 = *(const h4v*)(smem + KOFF + t * 512 + (st1 + kg * 4) * 2);
#pragma unroll
            for (int i = 0; i < 4; ++i) {
                acc0[i] = fmaf((float)k0[i], p0[i], acc0[i]);
                acc1[i] = fmaf((float)k1[i], p1[i], acc1[i]);
            }
            ++t;
        }
    }

#pragma unroll
    for (int i = 0; i < 4; ++i) { acc0[i] += bv; acc1[i] += bv; }

    // ---- transpose through LDS (aliases x region) for dense stores ----
    __syncthreads();
    float* outst = (float*)smem;               // [16 o][260 px]
    *(f4*)(outst + l15 * 260 + st0 + kg * 4) = acc0;
    *(f4*)(outst + l15 * 260 + st1 + kg * 4) = acc1;
    __syncthreads();

    const int o = tid >> 5;                    // 0..15
    const int p = (tid & 31) * 8;              // 0..248
    f4 v0 = *(const f4*)(outst + o * 260 + p);
    f4 v1 = *(const f4*)(outst + o * 260 + p + 4);
    const int mr = p >> 6, nc = p & 63;
    float* op = out + ((size_t)(bz * COUT + half * 16 + o)) * HW + (size_t)(tm + mr) * Ww + tn + nc;
    *(f4*)op = v0;
    *(f4*)(op + 4) = v1;
}

// ---------- fallback (R6 kernel, used only if ws_size too small) ----------
__global__ __launch_bounds__(512, 4) void pac_mfma2(
    const float* __restrict__ x, const float* __restrict__ guide,
    const float* __restrict__ weight, const float* __restrict__ bias,
    float* __restrict__ out)
{
    __shared__ __align__(16) unsigned char smem[SMEMB];
    const int tid  = threadIdx.x;
    const int bx   = blockIdx.x;
    const int half = blockIdx.y;
    const int bz   = blockIdx.z;
    const int tm = (bx >> 1) * TH;
    const int tn = (bx & 1) * TW;

    const float* xb = x + (size_t)bz * CIN * HW;
#pragma unroll
    for (int it = 0; it < 34; ++it) {
        const int idx  = it * 512 + tid;
        const int j    = idx / NSLOT;
        const int slot = idx - j * NSLOT;
        const int r    = slot / PRW;
        const int c    = slot - r * PRW;
        const int gm = tm + r - 2, gn = tn + c - 2;
        float v = 0.f;
        if ((unsigned)gm < (unsigned)Hh && (unsigned)gn < (unsigned)Ww)
            v = xb[(size_t)j * HW + gm * Ww + gn];
        *(_Float16*)(smem + XOFF + (j >> 3) * XJG + slot * 16 + (j & 7) * 2) = (_Float16)v;
    }
#pragma unroll
    for (int it = 0; it < 25; ++it) {
        const int idx = it * 512 + tid;
        const int o = idx & 15;
        const int j = (idx >> 4) & 31;
        const int t = idx >> 9;
        const float v = weight[(size_t)(half * 16 + o) * (CIN * KK * KK) + j * (KK * KK) + t];
        *(_Float16*)(smem + WOFF + t * 1024 + (j >> 3) * 256 + o * 16 + (j & 7) * 2) = (_Float16)v;
    }
    {
        const int px = tid & 255, th = tid >> 8;
        const int pr = px >> 6, pc = px & 63;
        const int m = tm + pr, n = tn + pc;
        const float* gb = guide + ((size_t)bz * CG) * HW + m * Ww + n;
        float center[CG];
#pragma unroll
        for (int c = 0; c < CG; ++c) center[c] = gb[c * HW];
        int t = 0;
#pragma unroll
        for (int k = 0; k < KK; ++k) {
            const int dm = k - 2;
            const bool rowok = ((unsigned)(m + dm) < (unsigned)Hh);
#pragma unroll
            for (int l = 0; l < KK; ++l) {
                if ((t < 13) == (th == 0)) {
                    const int dn = l - 2;
                    const bool ok = rowok && ((unsigned)(n + dn) < (unsigned)Ww);
                    float ss = 0.f;
#pragma unroll
                    for (int c = 0; c < CG; ++c) {
                        float gv = ok ? gb[c * HW + dm * Ww + dn] : 0.f;
                        float d = gv - center[c];
                        ss = fmaf(d, d, ss);
                    }
                    *(_Float16*)(smem + KOFF + t * 512 + px * 2) = (_Float16)__expf(-0.5f * ss);
                }
                ++t;
            }
        }
    }
    __syncthreads();
    const int lane = tid & 63;
    const int l15 = lane & 15, kg = lane >> 4;
    const int wv = tid >> 6;
    const int st0 = wv * 32, st1 = st0 + 16;
    const int r0 = wv >> 1;
    const int c00 = (wv & 1) * 32;
    f4 acc0 = {0.f, 0.f, 0.f, 0.f}, acc1 = {0.f, 0.f, 0.f, 0.f};
    const unsigned char* xg = smem + XOFF + kg * XJG;
    const float bv = bias[half * 16 + l15];
    int t = 0;
#pragma unroll
    for (int k = 0; k < KK; ++k) {
#pragma unroll
        for (int l = 0; l < KK; ++l) {
            const int abase = ((r0 + k) * PRW + c00 + l + l15) * 16;
            h8 A0 = *(const h8*)(xg + abase);
            h8 A1 = *(const h8*)(xg + abase + 256);
            h8 Bv = *(const h8*)(smem + WOFF + t * 1024 + kg * 256 + l15 * 16);
            f4 p0 = __builtin_amdgcn_mfma_f32_16x16x32_f16(A0, Bv, (f4){0.f,0.f,0.f,0.f}, 0, 0, 0);
            f4 p1 = __builtin_amdgcn_mfma_f32_16x16x32_f16(A1, Bv, (f4){0.f,0.f,0.f,0.f}, 0, 0, 0);
            h4v k0 = *(const h4v*)(smem + KOFF + t * 512 + (st0 + kg * 4) * 2);
            h4v k1 = *(const h4v*)(smem + KOFF + t * 512 + (st1 + kg * 4) * 2);
#pragma unroll
            for (int i = 0; i < 4; ++i) {
                acc0[i] = fmaf((float)k0[i], p0[i], acc0[i]);
                acc1[i] = fmaf((float)k1[i], p1[i], acc1[i]);
            }
            ++t;
        }
    }
#pragma unroll
    for (int i = 0; i < 4; ++i) { acc0[i] += bv; acc1[i] += bv; }
    __syncthreads();
    float* outst = (float*)smem;
    *(f4*)(outst + l15 * 260 + st0 + kg * 4) = acc0;
    *(f4*)(outst + l15 * 260 + st1 + kg * 4) = acc1;
    __syncthreads();
    const int o = tid >> 5;
    const int p = (tid & 31) * 8;
    f4 v0 = *(const f4*)(outst + o * 260 + p);
    f4 v1 = *(const f4*)(outst + o * 260 + p + 4);
    const int mr = p >> 6, nc = p & 63;
    float* op = out + ((size_t)(bz * COUT + half * 16 + o)) * HW + (size_t)(tm + mr) * Ww + tn + nc;
    *(f4*)op = v0;
    *(f4*)(op + 4) = v1;
}

extern "C" void kernel_launch(void* const* d_in, const int* in_sizes, int n_in,
                              void* d_out, int out_size, void* d_ws, size_t ws_size,
                              hipStream_t stream) {
    const float* x      = (const float*)d_in[0];
    const float* guide  = (const float*)d_in[1];
    const float* weight = (const float*)d_in[2];
    const float* bias   = (const float*)d_in[3];
    float* out = (float*)d_out;

    if (ws_size >= (size_t)WS_NEED) {
        _Float16* xt = (_Float16*)((char*)d_ws + XT_OFF);
        _Float16* wt = (_Float16*)((char*)d_ws + WT_OFF);
        _Float16* kw = (_Float16*)((char*)d_ws + KW_OFF);
        prep<<<dim3(818), 512, 0, stream>>>(x, guide, weight, xt, wt, kw);
        pac_mfma4<<<dim3(64, 2, Bn), 512, 0, stream>>>(xt, wt, kw, bias, out);
    } else {
        pac_mfma2<<<dim3(64, 2, Bn), 512, 0, stream>>>(x, guide, weight, bias, out);
    }
}

// Round 9
// 23.637 us; speedup vs baseline: 7.2608x; 1.0473x over previous
//
#include <hip/hip_runtime.h>

#define Bn   4
#define CIN  32
#define COUT 32
#define CG   8
#define Hh   128
#define Ww   128
#define KK   5
#define HW   (Hh * Ww)

#define TW   64     // tile 64 wide x 4 tall = 256 px per block
#define TH   4
#define PRW  68     // halo 68 x 8
#define PRH  8
#define NSLOT (PRW * PRH)   // 544

typedef _Float16 h8  __attribute__((ext_vector_type(8)));
typedef _Float16 h2  __attribute__((ext_vector_type(2)));
typedef float    f4  __attribute__((ext_vector_type(4)));

// LDS layout (bytes) — SoA over j-octets: fragment reads have 16B lane stride.
//   x:    [4 jg][544 slots] h8            : 34816
//   w:    [25 t][4 jg][16 o] h8           : 25600
//   kern: [25 t][8 g][16 i] u32-pairs     : 12800   (pair = kern[px], kern[px+16])
#define XOFF  0
#define XJG   8704
#define WOFF  34816
#define KOFF  60416
#define SMEMB 73216

// workspace (bytes)
#define XT_OFF 0                       // 4*16384*32*2 = 4,194,304
#define WT_OFF 4194304                 // 25600*2      =    51,200
#define KW_OFF 4245504                 // 4*64*25*256*2 = 3,276,800
#define WS_NEED 7522304

// ---------- fused pre-pass: x/w transpose + kern tiles (1 dispatch) ----------
__global__ __launch_bounds__(512) void prep(
    const float* __restrict__ x, const float* __restrict__ guide,
    const float* __restrict__ w,
    _Float16* __restrict__ xt, _Float16* __restrict__ wt, _Float16* __restrict__ kw)
{
    const int bid = blockIdx.x;
    const int tid = threadIdx.x;

    if (bid < 512) {
        // ---- region X: x[b][j][m][n] f32 -> xt[b][m][n][32j] f16 ----
        const int b = bid >> 7, m = bid & 127;
        const int n = tid & 127, jh = tid >> 7;       // jh = j-octet 0..3
        const float* xp = x + ((size_t)(b * CIN + jh * 8)) * HW + m * Ww + n;
        h8 v;
#pragma unroll
        for (int e = 0; e < 8; ++e) v[e] = (_Float16)xp[(size_t)e * HW];
        ((h8*)xt)[((size_t)b * HW + m * Ww + n) * 4 + jh] = v;
    } else if (bid < 562) {
        // ---- region W: w -> wt[half][t][jg][o][e] f16 (LDS image) ----
        const int idx = (bid - 512) * 512 + tid;      // 0..25599
        const int ht = idx >> 9;
        const int half = ht / 25, t = ht - half * 25;
        const int rem = idx & 511;
        const int jg = rem >> 7, o = (rem >> 3) & 15, e = rem & 7;
        wt[idx] = (_Float16)w[(size_t)(half * 16 + o) * (CIN * KK * KK) + (jg * 8 + e) * (KK * KK) + t];
    } else {
        // ---- region K: adaptive kernel per 64x4 tile -> paired layout ----
        // kw[tile][t][g][i] pair = (kern[t][g*32+i], kern[t][g*32+16+i])
        __shared__ __align__(16) _Float16 gl[NSLOT * 8];   // [slot][8c] h8, 8704 B
        const int tb = bid - 562;                     // 0..255
        const int tile = tb & 63, b = tb >> 6;
        const int tm = (tile >> 1) * TH, tn = (tile & 1) * TW;
        const float* gb = guide + (size_t)b * CG * HW;
#pragma unroll
        for (int it = 0; it < 2; ++it) {
            const int slot = it * 512 + tid;
            if (slot < NSLOT) {
                const int r = slot / PRW, c = slot - r * PRW;
                const int gm = tm + r - 2, gn = tn + c - 2;
                h8 v = {};
                if ((unsigned)gm < (unsigned)Hh && (unsigned)gn < (unsigned)Ww) {
#pragma unroll
                    for (int cg = 0; cg < 8; ++cg)
                        v[cg] = (_Float16)gb[(size_t)cg * HW + gm * Ww + gn];
                }
                *(h8*)(gl + slot * 8) = v;
            }
        }
        __syncthreads();
        const int px = tid & 255, th = tid >> 8;      // th=0: taps 0..12, th=1: 13..24
        const int pr = px >> 6, pc = px & 63;
        const int pg = px >> 5, ps = (px >> 4) & 1, pi = px & 15;   // pair coords
        const h8 c8 = *(const h8*)(gl + ((pr + 2) * PRW + pc + 2) * 8);
        float cg[8];
#pragma unroll
        for (int i = 0; i < 8; ++i) cg[i] = (float)c8[i];
        _Float16* kout = kw + ((size_t)(b * 64 + tile) * 25) * 256;
        int t = 0;
#pragma unroll
        for (int k = 0; k < KK; ++k) {
#pragma unroll
            for (int l = 0; l < KK; ++l) {
                if ((t < 13) == (th == 0)) {
                    const h8 gv = *(const h8*)(gl + ((pr + k) * PRW + pc + l) * 8);
                    float ss = 0.f;
#pragma unroll
                    for (int i = 0; i < 8; ++i) {
                        const float d = (float)gv[i] - cg[i];
                        ss = fmaf(d, d, ss);
                    }
                    kout[t * 256 + (pg * 16 + pi) * 2 + ps] = (_Float16)__expf(-0.5f * ss);
                }
                ++t;
            }
        }
    }
}

// ---------- main kernel: pure-copy staging, kern folded into A-operand ----------
__global__ __launch_bounds__(512, 4) void pac_mfma5(
    const _Float16* __restrict__ xt, const _Float16* __restrict__ wt,
    const _Float16* __restrict__ kw, const float* __restrict__ bias,
    float* __restrict__ out)
{
    __shared__ __align__(16) unsigned char smem[SMEMB];

    const int tid  = threadIdx.x;
    const int bx   = blockIdx.x;       // 0..63 spatial tiles (2 wide x 32 tall)
    const int half = blockIdx.y;       // 0..1 output half (16 ch)
    const int bz   = blockIdx.z;       // batch
    const int tm = (bx >> 1) * TH;
    const int tn = (bx & 1) * TW;

    // ---- stage x: 544 slots x 4 j-octets, b128 in / b128 out ----
    const int pxbase = bz * HW;
#pragma unroll
    for (int it = 0; it < 5; ++it) {
        const int idx = it * 512 + tid;            // over 2176 = 544*4
        if (idx < 2176) {
            const int slot = idx >> 2, jg = idx & 3;
            const int r = slot / PRW;
            const int c = slot - r * PRW;
            const int gm = tm + r - 2, gn = tn + c - 2;
            h8 v = {};
            if ((unsigned)gm < (unsigned)Hh && (unsigned)gn < (unsigned)Ww)
                v = *(const h8*)(xt + ((size_t)(pxbase + gm * Ww + gn)) * 32 + jg * 8);
            *(h8*)(smem + XOFF + jg * XJG + slot * 16) = v;
        }
    }

    // ---- stage w (o-half): linear b128 copy ----
    const h8* wth = (const h8*)(wt + half * 12800);
#pragma unroll
    for (int it = 0; it < 4; ++it) {
        const int idx = it * 512 + tid;            // over 1600 h8
        if (idx < 1600)
            *(h8*)(smem + WOFF + idx * 16) = wth[idx];
    }

    // ---- stage kern: linear b128 copy of this tile's 25x256 f16 (paired) ----
    const h8* ksrc = (const h8*)(kw + ((size_t)(bz * 64 + bx) * 25) * 256);
#pragma unroll
    for (int it = 0; it < 2; ++it) {
        const int idx = it * 512 + tid;            // over 800 h8
        if (idx < 800)
            *(h8*)(smem + KOFF + idx * 16) = ksrc[idx];
    }

    __syncthreads();

    // ---- main loop: per tap, scale A rows by kern (pk_mul), MFMA C-chain ----
    const int lane = tid & 63;
    const int l15 = lane & 15, kg = lane >> 4;
    const int wv = tid >> 6;                   // 8 waves
    const int st0 = wv * 32, st1 = st0 + 16;   // two 16-px M-subtiles (same row)
    const int r0 = wv >> 1;                    // tile row 0..3
    const int c00 = (wv & 1) * 32;             // col base 0/32

    f4 acc0 = {0.f, 0.f, 0.f, 0.f}, acc1 = {0.f, 0.f, 0.f, 0.f};
    const unsigned char* xg = smem + XOFF + kg * XJG;
    const int kbase = KOFF + (wv * 16 + l15) * 4;   // this lane's pair column
    const float bv = bias[half * 16 + l15];

    int t = 0;
#pragma unroll
    for (int k = 0; k < KK; ++k) {
#pragma unroll
        for (int l = 0; l < KK; ++l) {
            const int abase = ((r0 + k) * PRW + c00 + l + l15) * 16;
            h8 A0 = *(const h8*)(xg + abase);
            h8 A1 = *(const h8*)(xg + abase + 256);        // +16 cols
            h8 Bv = *(const h8*)(smem + WOFF + t * 1024 + kg * 256 + l15 * 16);
            h2 kk = *(const h2*)(smem + kbase + t * 512);  // (kern[px0], kern[px1])

            h8 A0s = A0 * kk[0];                           // 4x v_pk_mul_f16
            h8 A1s = A1 * kk[1];

            acc0 = __builtin_amdgcn_mfma_f32_16x16x32_f16(A0s, Bv, acc0, 0, 0, 0);
            acc1 = __builtin_amdgcn_mfma_f32_16x16x32_f16(A1s, Bv, acc1, 0, 0, 0);
            ++t;
        }
    }

#pragma unroll
    for (int i = 0; i < 4; ++i) { acc0[i] += bv; acc1[i] += bv; }

    // ---- transpose through LDS (aliases x region) for dense stores ----
    __syncthreads();
    float* outst = (float*)smem;               // [16 o][260 px]
    *(f4*)(outst + l15 * 260 + st0 + kg * 4) = acc0;
    *(f4*)(outst + l15 * 260 + st1 + kg * 4) = acc1;
    __syncthreads();

    const int o = tid >> 5;                    // 0..15
    const int p = (tid & 31) * 8;              // 0..248
    f4 v0 = *(const f4*)(outst + o * 260 + p);
    f4 v1 = *(const f4*)(outst + o * 260 + p + 4);
    const int mr = p >> 6, nc = p & 63;
    float* op = out + ((size_t)(bz * COUT + half * 16 + o)) * HW + (size_t)(tm + mr) * Ww + tn + nc;
    *(f4*)op = v0;
    *(f4*)(op + 4) = v1;
}

// ---------- fallback (R6 kernel, used only if ws_size too small) ----------
typedef _Float16 h4v __attribute__((ext_vector_type(4)));
__global__ __launch_bounds__(512, 4) void pac_mfma2(
    const float* __restrict__ x, const float* __restrict__ guide,
    const float* __restrict__ weight, const float* __restrict__ bias,
    float* __restrict__ out)
{
    __shared__ __align__(16) unsigned char smem[SMEMB];
    const int tid  = threadIdx.x;
    const int bx   = blockIdx.x;
    const int half = blockIdx.y;
    const int bz   = blockIdx.z;
    const int tm = (bx >> 1) * TH;
    const int tn = (bx & 1) * TW;

    const float* xb = x + (size_t)bz * CIN * HW;
#pragma unroll
    for (int it = 0; it < 34; ++it) {
        const int idx  = it * 512 + tid;
        const int j    = idx / NSLOT;
        const int slot = idx - j * NSLOT;
        const int r    = slot / PRW;
        const int c    = slot - r * PRW;
        const int gm = tm + r - 2, gn = tn + c - 2;
        float v = 0.f;
        if ((unsigned)gm < (unsigned)Hh && (unsigned)gn < (unsigned)Ww)
            v = xb[(size_t)j * HW + gm * Ww + gn];
        *(_Float16*)(smem + XOFF + (j >> 3) * XJG + slot * 16 + (j & 7) * 2) = (_Float16)v;
    }
#pragma unroll
    for (int it = 0; it < 25; ++it) {
        const int idx = it * 512 + tid;
        const int o = idx & 15;
        const int j = (idx >> 4) & 31;
        const int t = idx >> 9;
        const float v = weight[(size_t)(half * 16 + o) * (CIN * KK * KK) + j * (KK * KK) + t];
        *(_Float16*)(smem + WOFF + t * 1024 + (j >> 3) * 256 + o * 16 + (j & 7) * 2) = (_Float16)v;
    }
    {
        const int px = tid & 255, th = tid >> 8;
        const int pr = px >> 6, pc = px & 63;
        const int m = tm + pr, n = tn + pc;
        const float* gb = guide + ((size_t)bz * CG) * HW + m * Ww + n;
        float center[CG];
#pragma unroll
        for (int c = 0; c < CG; ++c) center[c] = gb[c * HW];
        int t = 0;
#pragma unroll
        for (int k = 0; k < KK; ++k) {
            const int dm = k - 2;
            const bool rowok = ((unsigned)(m + dm) < (unsigned)Hh);
#pragma unroll
            for (int l = 0; l < KK; ++l) {
                if ((t < 13) == (th == 0)) {
                    const int dn = l - 2;
                    const bool ok = rowok && ((unsigned)(n + dn) < (unsigned)Ww);
                    float ss = 0.f;
#pragma unroll
                    for (int c = 0; c < CG; ++c) {
                        float gv = ok ? gb[c * HW + dm * Ww + dn] : 0.f;
                        float d = gv - center[c];
                        ss = fmaf(d, d, ss);
                    }
                    *(_Float16*)(smem + KOFF + t * 512 + px * 2) = (_Float16)__expf(-0.5f * ss);
                }
                ++t;
            }
        }
    }
    __syncthreads();
    const int lane = tid & 63;
    const int l15 = lane & 15, kg = lane >> 4;
    const int wv = tid >> 6;
    const int st0 = wv * 32, st1 = st0 + 16;
    const int r0 = wv >> 1;
    const int c00 = (wv & 1) * 32;
    f4 acc0 = {0.f, 0.f, 0.f, 0.f}, acc1 = {0.f, 0.f, 0.f, 0.f};
    const unsigned char* xg = smem + XOFF + kg * XJG;
    const float bv = bias[half * 16 + l15];
    int t = 0;
#pragma unroll
    for (int k = 0; k < KK; ++k) {
#pragma unroll
        for (int l = 0; l < KK; ++l) {
            const int abase = ((r0 + k) * PRW + c00 + l + l15) * 16;
            h8 A0 = *(const h8*)(xg + abase);
            h8 A1 = *(const h8*)(xg + abase + 256);
            h8 Bv = *(const h8*)(smem + WOFF + t * 1024 + kg * 256 + l15 * 16);
            f4 p0 = __builtin_amdgcn_mfma_f32_16x16x32_f16(A0, Bv, (f4){0.f,0.f,0.f,0.f}, 0, 0, 0);
            f4 p1 = __builtin_amdgcn_mfma_f32_16x16x32_f16(A1, Bv, (f4){0.f,0.f,0.f,0.f}, 0, 0, 0);
            h4v k0 = *(const h4v*)(smem + KOFF + t * 512 + (st0 + kg * 4) * 2);
            h4v k1 = *(const h4v*)(smem + KOFF + t * 512 + (st1 + kg * 4) * 2);
#pragma unroll
            for (int i = 0; i < 4; ++i) {
                acc0[i] = fmaf((float)k0[i], p0[i], acc0[i]);
                acc1[i] = fmaf((float)k1[i], p1[i], acc1[i]);
            }
            ++t;
        }
    }
#pragma unroll
    for (int i = 0; i < 4; ++i) { acc0[i] += bv; acc1[i] += bv; }
    __syncthreads();
    float* outst = (float*)smem;
    *(f4*)(outst + l15 * 260 + st0 + kg * 4) = acc0;
    *(f4*)(outst + l15 * 260 + st1 + kg * 4) = acc1;
    __syncthreads();
    const int o = tid >> 5;
    const int p = (tid & 31) * 8;
    f4 v0 = *(const f4*)(outst + o * 260 + p);
    f4 v1 = *(const f4*)(outst + o * 260 + p + 4);
    const int mr = p >> 6, nc = p & 63;
    float* op = out + ((size_t)(bz * COUT + half * 16 + o)) * HW + (size_t)(tm + mr) * Ww + tn + nc;
    *(f4*)op = v0;
    *(f4*)(op + 4) = v1;
}

extern "C" void kernel_launch(void* const* d_in, const int* in_sizes, int n_in,
                              void* d_out, int out_size, void* d_ws, size_t ws_size,
                              hipStream_t stream) {
    const float* x      = (const float*)d_in[0];
    const float* guide  = (const float*)d_in[1];
    const float* weight = (const float*)d_in[2];
    const float* bias   = (const float*)d_in[3];
    float* out = (float*)d_out;

    if (ws_size >= (size_t)WS_NEED) {
        _Float16* xt = (_Float16*)((char*)d_ws + XT_OFF);
        _Float16* wt = (_Float16*)((char*)d_ws + WT_OFF);
        _Float16* kw = (_Float16*)((char*)d_ws + KW_OFF);
        prep<<<dim3(818), 512, 0, stream>>>(x, guide, weight, xt, wt, kw);
        pac_mfma5<<<dim3(64, 2, Bn), 512, 0, stream>>>(xt, wt, kw, bias, out);
    } else {
        pac_mfma2<<<dim3(64, 2, Bn), 512, 0, stream>>>(x, guide, weight, bias, out);
    }
}

// Round 10
// 23.599 us; speedup vs baseline: 7.2724x; 1.0016x over previous
//
#include <hip/hip_runtime.h>

#define Bn   4
#define CIN  32
#define COUT 32
#define CG   8
#define Hh   128
#define Ww   128
#define KK   5
#define HW   (Hh * Ww)

#define TW   64     // tile 64 wide x 4 tall = 256 px per block
#define TH   4
#define PRW  68     // halo 68 x 8
#define PRH  8
#define NSLOT (PRW * PRH)   // 544

typedef _Float16 h8  __attribute__((ext_vector_type(8)));
typedef _Float16 h2  __attribute__((ext_vector_type(2)));
typedef float    f4  __attribute__((ext_vector_type(4)));

// LDS layout (bytes) — SoA over j-octets: fragment reads have 16B lane stride.
//   x:    [4 jg][544 slots] h8            : 34816
//   w h0: [25 t][4 jg][16 o] h8           : 25600   (half1 lives in VGPRs, from global)
//   kern: [25 t][8 g][16 i] u32-pairs     : 12800
#define XOFF  0
#define XJG   8704
#define WOFF  34816
#define KOFF  60416
#define SMEMB 73216

// workspace (bytes)
#define XT_OFF 0                       // 4*16384*32*2 = 4,194,304
#define WT_OFF 4194304                 // 25600*2      =    51,200
#define KW_OFF 4245504                 // 4*64*25*256*2 = 3,276,800
#define WS_NEED 7522304

// ---------- fused pre-pass: x/w transpose + kern tiles (1 dispatch) ----------
__global__ __launch_bounds__(512) void prep(
    const float* __restrict__ x, const float* __restrict__ guide,
    const float* __restrict__ w,
    _Float16* __restrict__ xt, _Float16* __restrict__ wt, _Float16* __restrict__ kw)
{
    const int bid = blockIdx.x;
    const int tid = threadIdx.x;

    if (bid < 512) {
        // ---- region X: x[b][j][m][n] f32 -> xt[b][m][n][32j] f16 ----
        const int b = bid >> 7, m = bid & 127;
        const int n = tid & 127, jh = tid >> 7;       // jh = j-octet 0..3
        const float* xp = x + ((size_t)(b * CIN + jh * 8)) * HW + m * Ww + n;
        h8 v;
#pragma unroll
        for (int e = 0; e < 8; ++e) v[e] = (_Float16)xp[(size_t)e * HW];
        ((h8*)xt)[((size_t)b * HW + m * Ww + n) * 4 + jh] = v;
    } else if (bid < 562) {
        // ---- region W: w -> wt[half][t][jg][o][e] f16 (LDS image) ----
        const int idx = (bid - 512) * 512 + tid;      // 0..25599
        const int ht = idx >> 9;
        const int half = ht / 25, t = ht - half * 25;
        const int rem = idx & 511;
        const int jg = rem >> 7, o = (rem >> 3) & 15, e = rem & 7;
        wt[idx] = (_Float16)w[(size_t)(half * 16 + o) * (CIN * KK * KK) + (jg * 8 + e) * (KK * KK) + t];
    } else {
        // ---- region K: adaptive kernel per 64x4 tile -> paired layout ----
        // kw[tile][t][g][i] pair = (kern[t][g*32+i], kern[t][g*32+16+i])
        __shared__ __align__(16) _Float16 gl[NSLOT * 8];   // [slot][8c] h8, 8704 B
        const int tb = bid - 562;                     // 0..255
        const int tile = tb & 63, b = tb >> 6;
        const int tm = (tile >> 1) * TH, tn = (tile & 1) * TW;
        const float* gb = guide + (size_t)b * CG * HW;
#pragma unroll
        for (int it = 0; it < 2; ++it) {
            const int slot = it * 512 + tid;
            if (slot < NSLOT) {
                const int r = slot / PRW, c = slot - r * PRW;
                const int gm = tm + r - 2, gn = tn + c - 2;
                h8 v = {};
                if ((unsigned)gm < (unsigned)Hh && (unsigned)gn < (unsigned)Ww) {
#pragma unroll
                    for (int cg = 0; cg < 8; ++cg)
                        v[cg] = (_Float16)gb[(size_t)cg * HW + gm * Ww + gn];
                }
                *(h8*)(gl + slot * 8) = v;
            }
        }
        __syncthreads();
        const int px = tid & 255, th = tid >> 8;      // th=0: taps 0..12, th=1: 13..24
        const int pr = px >> 6, pc = px & 63;
        const int pg = px >> 5, ps = (px >> 4) & 1, pi = px & 15;   // pair coords
        const h8 c8 = *(const h8*)(gl + ((pr + 2) * PRW + pc + 2) * 8);
        float cg[8];
#pragma unroll
        for (int i = 0; i < 8; ++i) cg[i] = (float)c8[i];
        _Float16* kout = kw + ((size_t)(b * 64 + tile) * 25) * 256;
        int t = 0;
#pragma unroll
        for (int k = 0; k < KK; ++k) {
#pragma unroll
            for (int l = 0; l < KK; ++l) {
                if ((t < 13) == (th == 0)) {
                    const h8 gv = *(const h8*)(gl + ((pr + k) * PRW + pc + l) * 8);
                    float ss = 0.f;
#pragma unroll
                    for (int i = 0; i < 8; ++i) {
                        const float d = (float)gv[i] - cg[i];
                        ss = fmaf(d, d, ss);
                    }
                    kout[t * 256 + (pg * 16 + pi) * 2 + ps] = (_Float16)__expf(-0.5f * ss);
                }
                ++t;
            }
        }
    }
}

// ---------- main kernel: 32-o blocks, A scaled once feeds 4 MFMA chains ----------
__global__ __launch_bounds__(512, 2) void pac_mfma6(
    const _Float16* __restrict__ xt, const _Float16* __restrict__ wt,
    const _Float16* __restrict__ kw, const float* __restrict__ bias,
    float* __restrict__ out)
{
    __shared__ __align__(16) unsigned char smem[SMEMB];

    const int tid = threadIdx.x;
    const int bx  = blockIdx.x;        // 0..63 spatial tiles (2 wide x 32 tall)
    const int bz  = blockIdx.y;        // batch
    const int tm = (bx >> 1) * TH;
    const int tn = (bx & 1) * TW;

    const int lane = tid & 63;
    const int l15 = lane & 15, kg = lane >> 4;

    // ---- preload half1 B-fragments into registers (global, L2-hot, no LDS) ----
    const h8* wh1 = (const h8*)wt + 1600;      // half1 = elements [12800,25600)
    h8 B1r[25];
#pragma unroll
    for (int t = 0; t < 25; ++t)
        B1r[t] = wh1[t * 64 + kg * 16 + l15];

    // ---- stage x: 544 slots x 4 j-octets, b128 in / b128 out ----
    const int pxbase = bz * HW;
#pragma unroll
    for (int it = 0; it < 5; ++it) {
        const int idx = it * 512 + tid;            // over 2176 = 544*4
        if (idx < 2176) {
            const int slot = idx >> 2, jg = idx & 3;
            const int r = slot / PRW;
            const int c = slot - r * PRW;
            const int gm = tm + r - 2, gn = tn + c - 2;
            h8 v = {};
            if ((unsigned)gm < (unsigned)Hh && (unsigned)gn < (unsigned)Ww)
                v = *(const h8*)(xt + ((size_t)(pxbase + gm * Ww + gn)) * 32 + jg * 8);
            *(h8*)(smem + XOFF + jg * XJG + slot * 16) = v;
        }
    }

    // ---- stage w half0: linear b128 copy ----
    const h8* wth = (const h8*)wt;
#pragma unroll
    for (int it = 0; it < 4; ++it) {
        const int idx = it * 512 + tid;            // over 1600 h8
        if (idx < 1600)
            *(h8*)(smem + WOFF + idx * 16) = wth[idx];
    }

    // ---- stage kern: linear b128 copy of this tile's 25x256 f16 (paired) ----
    const h8* ksrc = (const h8*)(kw + ((size_t)(bz * 64 + bx) * 25) * 256);
#pragma unroll
    for (int it = 0; it < 2; ++it) {
        const int idx = it * 512 + tid;            // over 800 h8
        if (idx < 800)
            *(h8*)(smem + KOFF + idx * 16) = ksrc[idx];
    }

    __syncthreads();

    // ---- main loop: scale A once, 4 MFMA chains (2 subtiles x 2 o-halves) ----
    const int wv = tid >> 6;                   // 8 waves
    const int st0 = wv * 32, st1 = st0 + 16;   // two 16-px M-subtiles (same row)
    const int r0 = wv >> 1;                    // tile row 0..3
    const int c00 = (wv & 1) * 32;             // col base 0/32

    f4 acc00 = {0.f,0.f,0.f,0.f}, acc01 = {0.f,0.f,0.f,0.f};
    f4 acc10 = {0.f,0.f,0.f,0.f}, acc11 = {0.f,0.f,0.f,0.f};
    const unsigned char* xg = smem + XOFF + kg * XJG;
    const int kbase = KOFF + (wv * 16 + l15) * 4;   // this lane's pair column

    int t = 0;
#pragma unroll
    for (int k = 0; k < KK; ++k) {
#pragma unroll
        for (int l = 0; l < KK; ++l) {
            const int abase = ((r0 + k) * PRW + c00 + l + l15) * 16;
            h8 A0 = *(const h8*)(xg + abase);
            h8 A1 = *(const h8*)(xg + abase + 256);        // +16 cols
            h8 B0 = *(const h8*)(smem + WOFF + t * 1024 + kg * 256 + l15 * 16);
            h2 kk = *(const h2*)(smem + kbase + t * 512);  // (kern[px0], kern[px1])

            h8 A0s = A0 * kk[0];                           // 4x v_pk_mul_f16 each
            h8 A1s = A1 * kk[1];

            acc00 = __builtin_amdgcn_mfma_f32_16x16x32_f16(A0s, B0,      acc00, 0, 0, 0);
            acc01 = __builtin_amdgcn_mfma_f32_16x16x32_f16(A0s, B1r[t],  acc01, 0, 0, 0);
            acc10 = __builtin_amdgcn_mfma_f32_16x16x32_f16(A1s, B0,      acc10, 0, 0, 0);
            acc11 = __builtin_amdgcn_mfma_f32_16x16x32_f16(A1s, B1r[t],  acc11, 0, 0, 0);
            ++t;
        }
    }

    const float bv0 = bias[l15], bv1 = bias[16 + l15];
#pragma unroll
    for (int i = 0; i < 4; ++i) {
        acc00[i] += bv0; acc10[i] += bv0;
        acc01[i] += bv1; acc11[i] += bv1;
    }

    // ---- transpose through LDS (aliases x region) for dense stores ----
    __syncthreads();
    float* outst = (float*)smem;               // [32 o][260 px] = 33280 B
    *(f4*)(outst + l15 * 260 + st0 + kg * 4) = acc00;
    *(f4*)(outst + l15 * 260 + st1 + kg * 4) = acc10;
    *(f4*)(outst + (16 + l15) * 260 + st0 + kg * 4) = acc01;
    *(f4*)(outst + (16 + l15) * 260 + st1 + kg * 4) = acc11;
    __syncthreads();

    const int o = tid >> 4;                    // 0..31
    const int i = tid & 15;
    float* op = out + ((size_t)(bz * COUT + o)) * HW;
#pragma unroll
    for (int c = 0; c < 4; ++c) {              // 4 rows of the tile
        f4 v = *(const f4*)(outst + o * 260 + c * 64 + i * 4);
        *(f4*)(op + (size_t)(tm + c) * Ww + tn + i * 4) = v;
    }
}

// ---------- fallback (R6 kernel, used only if ws_size too small) ----------
typedef _Float16 h4v __attribute__((ext_vector_type(4)));
__global__ __launch_bounds__(512, 4) void pac_mfma2(
    const float* __restrict__ x, const float* __restrict__ guide,
    const float* __restrict__ weight, const float* __restrict__ bias,
    float* __restrict__ out)
{
    __shared__ __align__(16) unsigned char smem[SMEMB];
    const int tid  = threadIdx.x;
    const int bx   = blockIdx.x;
    const int half = blockIdx.y;
    const int bz   = blockIdx.z;
    const int tm = (bx >> 1) * TH;
    const int tn = (bx & 1) * TW;

    const float* xb = x + (size_t)bz * CIN * HW;
#pragma unroll
    for (int it = 0; it < 34; ++it) {
        const int idx  = it * 512 + tid;
        const int j    = idx / NSLOT;
        const int slot = idx - j * NSLOT;
        const int r    = slot / PRW;
        const int c    = slot - r * PRW;
        const int gm = tm + r - 2, gn = tn + c - 2;
        float v = 0.f;
        if ((unsigned)gm < (unsigned)Hh && (unsigned)gn < (unsigned)Ww)
            v = xb[(size_t)j * HW + gm * Ww + gn];
        *(_Float16*)(smem + XOFF + (j >> 3) * XJG + slot * 16 + (j & 7) * 2) = (_Float16)v;
    }
#pragma unroll
    for (int it = 0; it < 25; ++it) {
        const int idx = it * 512 + tid;
        const int o = idx & 15;
        const int j = (idx >> 4) & 31;
        const int t = idx >> 9;
        const float v = weight[(size_t)(half * 16 + o) * (CIN * KK * KK) + j * (KK * KK) + t];
        *(_Float16*)(smem + WOFF + t * 1024 + (j >> 3) * 256 + o * 16 + (j & 7) * 2) = (_Float16)v;
    }
    {
        const int px = tid & 255, th = tid >> 8;
        const int pr = px >> 6, pc = px & 63;
        const int m = tm + pr, n = tn + pc;
        const float* gb = guide + ((size_t)bz * CG) * HW + m * Ww + n;
        float center[CG];
#pragma unroll
        for (int c = 0; c < CG; ++c) center[c] = gb[c * HW];
        int t = 0;
#pragma unroll
        for (int k = 0; k < KK; ++k) {
            const int dm = k - 2;
            const bool rowok = ((unsigned)(m + dm) < (unsigned)Hh);
#pragma unroll
            for (int l = 0; l < KK; ++l) {
                if ((t < 13) == (th == 0)) {
                    const int dn = l - 2;
                    const bool ok = rowok && ((unsigned)(n + dn) < (unsigned)Ww);
                    float ss = 0.f;
#pragma unroll
                    for (int c = 0; c < CG; ++c) {
                        float gv = ok ? gb[c * HW + dm * Ww + dn] : 0.f;
                        float d = gv - center[c];
                        ss = fmaf(d, d, ss);
                    }
                    *(_Float16*)(smem + KOFF + t * 512 + px * 2) = (_Float16)__expf(-0.5f * ss);
                }
                ++t;
            }
        }
    }
    __syncthreads();
    const int lane = tid & 63;
    const int l15 = lane & 15, kg = lane >> 4;
    const int wv = tid >> 6;
    const int st0 = wv * 32, st1 = st0 + 16;
    const int r0 = wv >> 1;
    const int c00 = (wv & 1) * 32;
    f4 acc0 = {0.f, 0.f, 0.f, 0.f}, acc1 = {0.f, 0.f, 0.f, 0.f};
    const unsigned char* xg = smem + XOFF + kg * XJG;
    const float bv = bias[half * 16 + l15];
    int t = 0;
#pragma unroll
    for (int k = 0; k < KK; ++k) {
#pragma unroll
        for (int l = 0; l < KK; ++l) {
            const int abase = ((r0 + k) * PRW + c00 + l + l15) * 16;
            h8 A0 = *(const h8*)(xg + abase);
            h8 A1 = *(const h8*)(xg + abase + 256);
            h8 Bv = *(const h8*)(smem + WOFF + t * 1024 + kg * 256 + l15 * 16);
            f4 p0 = __builtin_amdgcn_mfma_f32_16x16x32_f16(A0, Bv, (f4){0.f,0.f,0.f,0.f}, 0, 0, 0);
            f4 p1 = __builtin_amdgcn_mfma_f32_16x16x32_f16(A1, Bv, (f4){0.f,0.f,0.f,0.f}, 0, 0, 0);
            h4v k0 = *(const h4v*)(smem + KOFF + t * 512 + (st0 + kg * 4) * 2);
            h4v k1 = *(const h4v*)(smem + KOFF + t * 512 + (st1 + kg * 4) * 2);
#pragma unroll
            for (int i = 0; i < 4; ++i) {
                acc0[i] = fmaf((float)k0[i], p0[i], acc0[i]);
                acc1[i] = fmaf((float)k1[i], p1[i], acc1[i]);
            }
            ++t;
        }
    }
#pragma unroll
    for (int i = 0; i < 4; ++i) { acc0[i] += bv; acc1[i] += bv; }
    __syncthreads();
    float* outst = (float*)smem;
    *(f4*)(outst + l15 * 260 + st0 + kg * 4) = acc0;
    *(f4*)(outst + l15 * 260 + st1 + kg * 4) = acc1;
    __syncthreads();
    const int o = tid >> 5;
    const int p = (tid & 31) * 8;
    f4 v0 = *(const f4*)(outst + o * 260 + p);
    f4 v1 = *(const f4*)(outst + o * 260 + p + 4);
    const int mr = p >> 6, nc = p & 63;
    float* op = out + ((size_t)(bz * COUT + half * 16 + o)) * HW + (size_t)(tm + mr) * Ww + tn + nc;
    *(f4*)op = v0;
    *(f4*)(op + 4) = v1;
}

extern "C" void kernel_launch(void* const* d_in, const int* in_sizes, int n_in,
                              void* d_out, int out_size, void* d_ws, size_t ws_size,
                              hipStream_t stream) {
    const float* x      = (const float*)d_in[0];
    const float* guide  = (const float*)d_in[1];
    const float* weight = (const float*)d_in[2];
    const float* bias   = (const float*)d_in[3];
    float* out = (float*)d_out;

    if (ws_size >= (size_t)WS_NEED) {
        _Float16* xt = (_Float16*)((char*)d_ws + XT_OFF);
        _Float16* wt = (_Float16*)((char*)d_ws + WT_OFF);
        _Float16* kw = (_Float16*)((char*)d_ws + KW_OFF);
        prep<<<dim3(818), 512, 0, stream>>>(x, guide, weight, xt, wt, kw);
        pac_mfma6<<<dim3(64, Bn), 512, 0, stream>>>(xt, wt, kw, bias, out);
    } else {
        pac_mfma2<<<dim3(64, 2, Bn), 512, 0, stream>>>(x, guide, weight, bias, out);
    }
}